// Round 6
// baseline (286.107 us; speedup 1.0000x reference)
//
#include <hip/hip_runtime.h>
#include <hip/hip_bf16.h>

#define VIS_DIM 2048
#define TXT_DIM 1024
#define HID     1024
#define NB      128          // batch
#define NR      256          // regions
#define M_TOT   (NB*NR)      // 32768

typedef __attribute__((ext_vector_type(4))) float  f32x4;
typedef __attribute__((ext_vector_type(8))) short  short8;   // 8 x bf16 (4 VGPR)
typedef __attribute__((ext_vector_type(4))) unsigned short u16x4;

static __device__ __forceinline__ unsigned short f2bf(float f) {
    union { __hip_bfloat16 h; unsigned short u; } c;
    c.h = __float2bfloat16(f);
    return c.u;
}

static __device__ __forceinline__ float tanh_fast(float x) {
    float xc = fminf(fmaxf(x, -15.f), 15.f);
    float e  = __expf(2.f * xc);
    return (e - 1.f) / (e + 1.f);
}

// ---------------------------------------------------------------------------
// init: zero scores, t = bt broadcast (atomics accumulate on top)
// ---------------------------------------------------------------------------
__global__ void init_ws(float* __restrict__ scores, float* __restrict__ tbuf,
                        const float* __restrict__ bt) {
    int i = blockIdx.x * 256 + threadIdx.x;        // grid covers 131072
    if (i < M_TOT) scores[i] = 0.f;
    tbuf[i] = bt[i & (HID - 1)];
}

// ---------------------------------------------------------------------------
// t = text @ Wt^T (+bt already in tbuf). Split-K fp32 tiled GEMM, atomicAdd.
// ---------------------------------------------------------------------------
__global__ __launch_bounds__(256) void gemm_text(const float* __restrict__ text,
                                                 const float* __restrict__ Wt,
                                                 float* __restrict__ tbuf) {
    __shared__ float As[128][33];
    __shared__ float Bs[32][33];
    const int n0  = blockIdx.x * 32;
    const int k0  = blockIdx.y * 256;
    const int tid = threadIdx.x;
    const int tm  = tid >> 3;
    const int tn  = tid & 7;
    float acc[4][4] = {};
    for (int kt = 0; kt < 8; ++kt) {
        const int k = k0 + kt * 32;
        {   // stage A: 128x32
            int row = tid >> 1, off = (tid & 1) * 16;
            const float* src = text + row * TXT_DIM + k + off;
            #pragma unroll
            for (int j = 0; j < 4; ++j) {
                f32x4 v = *(const f32x4*)(src + j * 4);
                As[row][off + j*4 + 0] = v.x; As[row][off + j*4 + 1] = v.y;
                As[row][off + j*4 + 2] = v.z; As[row][off + j*4 + 3] = v.w;
            }
        }
        {   // stage B: 32x32
            int row = tid >> 3, off = (tid & 7) * 4;
            f32x4 v = *(const f32x4*)(Wt + (size_t)(n0 + row) * TXT_DIM + k + off);
            Bs[row][off + 0] = v.x; Bs[row][off + 1] = v.y;
            Bs[row][off + 2] = v.z; Bs[row][off + 3] = v.w;
        }
        __syncthreads();
        #pragma unroll
        for (int kk = 0; kk < 32; ++kk) {
            float a[4], b[4];
            #pragma unroll
            for (int i = 0; i < 4; ++i) a[i] = As[tm*4 + i][kk];
            #pragma unroll
            for (int j = 0; j < 4; ++j) b[j] = Bs[tn*4 + j][kk];
            #pragma unroll
            for (int i = 0; i < 4; ++i)
                #pragma unroll
                for (int j = 0; j < 4; ++j) acc[i][j] += a[i] * b[j];
        }
        __syncthreads();
    }
    #pragma unroll
    for (int i = 0; i < 4; ++i)
        #pragma unroll
        for (int j = 0; j < 4; ++j)
            atomicAdd(&tbuf[(tm*4 + i) * HID + n0 + tn*4 + j], acc[i][j]);
}

// ---------------------------------------------------------------------------
// Main fused GEMM: scores[row] += sum_col Wa[col]*tanh(A@Wv^T + bv + t)
// R6: depth-3 pipeline. Three asm stage sets (0,1,2) rotating, steady-state
// s_waitcnt vmcnt(16): the drained batch was issued TWO iterations (~1300cy)
// earlier >= 900cy HBM miss latency (R5's depth-2 gave only ~800cy; FETCH
// 600MB shows most loads miss to HBM). Period-6 hand-unrolled body keeps all
// set/buffer indices static (rule #20). Cost: ~220 VGPR -> 2 waves/SIMD;
// ILP replaces the lost TLP.
// ---------------------------------------------------------------------------
#define BK 32
#define NT (VIS_DIM / BK)    // 64

// byte offset inside one 8 KB bf16 tile [128 rows][32 k], 16B-slot swizzled
// (row stride 64 B: row bit0 is addr bit6, so XOR uses (row>>1)&3)
static __device__ __forceinline__ int tile_off(int row, int kElem) {
    return row * 64 + (((kElem >> 3) ^ ((row >> 1) & 3)) << 4);
}

__global__ __launch_bounds__(256, 2) void gemm_vis(
        const float* __restrict__ A,     // visual  32768 x 2048
        const float* __restrict__ Bv,    // Wv      1024 x 2048
        const float* __restrict__ bv,
        const float* __restrict__ wa,    // Wa[0]   1024
        const float* __restrict__ tbuf,  // 128 x 1024
        float* __restrict__ scores) {
    __shared__ __align__(16) char lds[32768];   // 2 buf x (A 8KB + B 8KB)

    // XCD-chunked mapping: xcd = wg&7 (HW round-robin), each XCD walks its
    // 256 local blocks n-fastest so nb=0..7 siblings of one mb are adjacent.
    const int wg   = blockIdx.x;
    const int xcd  = wg & 7;
    const int loc  = wg >> 3;               // 0..255
    const int mb   = xcd * 32 + (loc >> 3); // 0..255
    const int nb   = loc & 7;               // 0..7
    const int brow = mb * 128;
    const int bcol = nb * 128;

    const int tid  = threadIdx.x;
    const int lane = tid & 63;
    const int wid  = tid >> 6;
    const int wr   = wid >> 1, wc = wid & 1;   // 2x2 waves of 64x64

    // staging map: load r (0..3): row = (tid>>3)+32r, sfs = tid&7 (f32x4 slot)
    const int srow = tid >> 3;
    const int sfs  = tid & 7;
    // 32-bit byte voffsets into A / Bv (max 256 MB / 8 MB: fits u32)
    unsigned va0 = ((unsigned)(brow + srow      ) * VIS_DIM + sfs * 4) * 4u;
    unsigned va1 = va0 + 32u * VIS_DIM * 4u;
    unsigned va2 = va0 + 64u * VIS_DIM * 4u;
    unsigned va3 = va0 + 96u * VIS_DIM * 4u;
    unsigned vb0 = ((unsigned)(bcol + srow      ) * VIS_DIM + sfs * 4) * 4u;
    unsigned vb1 = vb0 + 32u * VIS_DIM * 4u;
    unsigned vb2 = vb0 + 64u * VIS_DIM * 4u;
    unsigned vb3 = vb0 + 96u * VIS_DIM * 4u;

    // LDS write byte offsets (within a tile) per r: 8B granule, swizzled
    int wbyte[4];
    #pragma unroll
    for (int r = 0; r < 4; ++r) {
        int row = srow + 32 * r;
        wbyte[r] = row * 64 + (((sfs >> 1) ^ ((row >> 1) & 3)) << 4) + (sfs & 1) * 8;
    }

    // Three stage sets, rotating: tile t lives in set (t % 3).
    f32x4 xA0, xA1, xA2, xA3, xB0, xB1, xB2, xB3;   // set 0
    f32x4 yA0, yA1, yA2, yA3, yB0, yB1, yB2, yB3;   // set 1
    f32x4 zA0, zA1, zA2, zA3, zB0, zB1, zB2, zB3;   // set 2
    f32x4 acc[4][4] = {};

#define GLOAD_SET(dA0,dA1,dA2,dA3,dB0,dB1,dB2,dB3)                             \
    do {                                                                       \
        asm volatile("global_load_dwordx4 %0, %1, %2"                          \
                     : "=&v"(dA0) : "v"(va0), "s"(A) : "memory");              \
        asm volatile("global_load_dwordx4 %0, %1, %2"                          \
                     : "=&v"(dA1) : "v"(va1), "s"(A) : "memory");              \
        asm volatile("global_load_dwordx4 %0, %1, %2"                          \
                     : "=&v"(dA2) : "v"(va2), "s"(A) : "memory");              \
        asm volatile("global_load_dwordx4 %0, %1, %2"                          \
                     : "=&v"(dA3) : "v"(va3), "s"(A) : "memory");              \
        asm volatile("global_load_dwordx4 %0, %1, %2"                          \
                     : "=&v"(dB0) : "v"(vb0), "s"(Bv) : "memory");             \
        asm volatile("global_load_dwordx4 %0, %1, %2"                          \
                     : "=&v"(dB1) : "v"(vb1), "s"(Bv) : "memory");             \
        asm volatile("global_load_dwordx4 %0, %1, %2"                          \
                     : "=&v"(dB2) : "v"(vb2), "s"(Bv) : "memory");             \
        asm volatile("global_load_dwordx4 %0, %1, %2"                          \
                     : "=&v"(dB3) : "v"(vb3), "s"(Bv) : "memory");             \
        va0 += BK * 4; va1 += BK * 4; va2 += BK * 4; va3 += BK * 4;            \
        vb0 += BK * 4; vb1 += BK * 4; vb2 += BK * 4; vb3 += BK * 4;            \
    } while (0)

#define GLOAD_0() GLOAD_SET(xA0,xA1,xA2,xA3,xB0,xB1,xB2,xB3)
#define GLOAD_1() GLOAD_SET(yA0,yA1,yA2,yA3,yB0,yB1,yB2,yB3)
#define GLOAD_2() GLOAD_SET(zA0,zA1,zA2,zA3,zB0,zB1,zB2,zB3)

    // Counted wait + compiler-motion fences (rule #18).
#define VWAIT(N)                                                               \
    do {                                                                       \
        __builtin_amdgcn_sched_barrier(0);                                     \
        asm volatile("s_waitcnt vmcnt(" #N ")" ::: "memory");                  \
        __builtin_amdgcn_sched_barrier(0);                                     \
    } while (0)

#define CVT8(dst, v0)                                                          \
    do {                                                                       \
        u16x4 t_;                                                              \
        t_.x = f2bf((v0).x); t_.y = f2bf((v0).y);                              \
        t_.z = f2bf((v0).z); t_.w = f2bf((v0).w);                              \
        dst = t_;                                                              \
    } while (0)

#define LWRITE_SET(bufbase, dA0,dA1,dA2,dA3,dB0,dB1,dB2,dB3)                   \
    do {                                                                       \
        u16x4 w_;                                                              \
        char* la = lds + (bufbase);                                            \
        char* lb = lds + (bufbase) + 8192;                                     \
        CVT8(w_, dA0); *(u16x4*)(la + wbyte[0]) = w_;                          \
        CVT8(w_, dA1); *(u16x4*)(la + wbyte[1]) = w_;                          \
        CVT8(w_, dA2); *(u16x4*)(la + wbyte[2]) = w_;                          \
        CVT8(w_, dA3); *(u16x4*)(la + wbyte[3]) = w_;                          \
        CVT8(w_, dB0); *(u16x4*)(lb + wbyte[0]) = w_;                          \
        CVT8(w_, dB1); *(u16x4*)(lb + wbyte[1]) = w_;                          \
        CVT8(w_, dB2); *(u16x4*)(lb + wbyte[2]) = w_;                          \
        CVT8(w_, dB3); *(u16x4*)(lb + wbyte[3]) = w_;                          \
    } while (0)

#define LWRITE_0(b) LWRITE_SET(b, xA0,xA1,xA2,xA3,xB0,xB1,xB2,xB3)
#define LWRITE_1(b) LWRITE_SET(b, yA0,yA1,yA2,yA3,yB0,yB1,yB2,yB3)
#define LWRITE_2(b) LWRITE_SET(b, zA0,zA1,zA2,zA3,zB0,zB1,zB2,zB3)

#define COMPUTE(bufbase)                                                       \
    do {                                                                       \
        short8 af[4], bf[4];                                                   \
        const int kk = (lane >> 4) * 8;                                        \
        const char* la = lds + (bufbase);                                      \
        const char* lb = lds + (bufbase) + 8192;                               \
        _Pragma("unroll")                                                      \
        for (int m = 0; m < 4; ++m)                                            \
            af[m] = *(const short8*)(la + tile_off(wr*64 + m*16 + (lane&15), kk)); \
        _Pragma("unroll")                                                      \
        for (int n = 0; n < 4; ++n)                                            \
            bf[n] = *(const short8*)(lb + tile_off(wc*64 + n*16 + (lane&15), kk)); \
        _Pragma("unroll")                                                      \
        for (int m = 0; m < 4; ++m)                                            \
            _Pragma("unroll")                                                  \
            for (int n = 0; n < 4; ++n)                                        \
                acc[m][n] = __builtin_amdgcn_mfma_f32_16x16x32_bf16(           \
                    af[m], bf[n], acc[m][n], 0, 0, 0);                         \
    } while (0)

    // Prologue: tiles 0,1 issued; tile0 staged; tile2 issued. Outstanding=16.
    GLOAD_0();                 // tile 0
    GLOAD_1();                 // tile 1   (outstanding 16)
    VWAIT(8);                  // set0 (tile 0) ready
    LWRITE_0(0);
    GLOAD_2();                 // tile 2   (outstanding 16 again after drain)
    __syncthreads();

    // Steady state, period 6 (3 sets x 2 LDS buffers). Invariant at each
    // body top: buf(t&1) holds tile t; sets (t+1)%3,(t+2)%3 in flight (=16).
    // Body: issue tile t+3 into set t%3 (24 out), compute tile t,
    // vmcnt(16) -> tile t+1 ready (issued 2 iters ago), stage it, barrier.
    #pragma unroll 1
    for (int t = 0; t < NT - 4; t += 6) {
        GLOAD_0(); COMPUTE(0);     VWAIT(16); LWRITE_1(16384); __syncthreads();
        GLOAD_1(); COMPUTE(16384); VWAIT(16); LWRITE_2(0);     __syncthreads();
        GLOAD_2(); COMPUTE(0);     VWAIT(16); LWRITE_0(16384); __syncthreads();
        GLOAD_0(); COMPUTE(16384); VWAIT(16); LWRITE_1(0);     __syncthreads();
        GLOAD_1(); COMPUTE(0);     VWAIT(16); LWRITE_2(16384); __syncthreads();
        GLOAD_2(); COMPUTE(16384); VWAIT(16); LWRITE_0(0);     __syncthreads();
    }
    // Tail: t = 60..63 (no further issues except tile 63 at t=60).
    GLOAD_0();                 // tile 63  (outstanding 24)
    COMPUTE(0);                // tile 60
    VWAIT(16); LWRITE_1(16384); __syncthreads();
    COMPUTE(16384);            // tile 61
    VWAIT(8);  LWRITE_2(0);     __syncthreads();
    COMPUTE(0);                // tile 62
    VWAIT(0);  LWRITE_0(16384); __syncthreads();
    COMPUTE(16384);            // tile 63
#undef GLOAD_SET
#undef GLOAD_0
#undef GLOAD_1
#undef GLOAD_2
#undef VWAIT
#undef CVT8
#undef LWRITE_SET
#undef LWRITE_0
#undef LWRITE_1
#undef LWRITE_2
#undef COMPUTE

    // ---- epilogue: tanh + Wa-dot, reduce over 16 cols/lane-group, atomicAdd
    const int b = brow >> 8;                 // batch index (tile fits in one b)
    float wa_c[4], bvt_c[4];
    #pragma unroll
    for (int n = 0; n < 4; ++n) {
        int col = bcol + wc * 64 + n * 16 + (lane & 15);
        wa_c[n]  = wa[col];
        bvt_c[n] = bv[col] + tbuf[b * HID + col];
    }
    #pragma unroll
    for (int m = 0; m < 4; ++m) {
        float p0 = 0.f, p1 = 0.f, p2 = 0.f, p3 = 0.f;
        #pragma unroll
        for (int n = 0; n < 4; ++n) {
            f32x4 v = acc[m][n];
            p0 += wa_c[n] * tanh_fast(v.x + bvt_c[n]);
            p1 += wa_c[n] * tanh_fast(v.y + bvt_c[n]);
            p2 += wa_c[n] * tanh_fast(v.z + bvt_c[n]);
            p3 += wa_c[n] * tanh_fast(v.w + bvt_c[n]);
        }
        #pragma unroll
        for (int d = 1; d < 16; d <<= 1) {
            p0 += __shfl_xor(p0, d); p1 += __shfl_xor(p1, d);
            p2 += __shfl_xor(p2, d); p3 += __shfl_xor(p3, d);
        }
        if ((lane & 15) == 0) {
            int rowg = brow + wr * 64 + m * 16 + (lane >> 4) * 4;
            atomicAdd(&scores[rowg + 0], p0);
            atomicAdd(&scores[rowg + 1], p1);
            atomicAdd(&scores[rowg + 2], p2);
            atomicAdd(&scores[rowg + 3], p3);
        }
    }
}

// ---------------------------------------------------------------------------
// softmax over regions + attended = w . visual ; grid (8 d-chunks, 128 b)
// ---------------------------------------------------------------------------
__global__ __launch_bounds__(256) void attend(const float* __restrict__ visual,
                                              const float* __restrict__ scores,
                                              float* __restrict__ out) {
    const int chunk = blockIdx.x;   // 0..7 -> 256 d each
    const int b     = blockIdx.y;   // 0..127
    const int tid   = threadIdx.x;
    const int lane  = tid & 63;
    const int wv    = tid >> 6;

    __shared__ float wsm[NR];
    __shared__ float red[4];
    __shared__ f32x4 part[4][64];

    float s = scores[b * NR + tid];
    float mx = s;
    #pragma unroll
    for (int d = 1; d < 64; d <<= 1) mx = fmaxf(mx, __shfl_xor(mx, d));
    if (lane == 0) red[wv] = mx;
    __syncthreads();
    mx = fmaxf(fmaxf(red[0], red[1]), fmaxf(red[2], red[3]));
    float e = __expf(s - mx);
    float sum = e;
    #pragma unroll
    for (int d = 1; d < 64; d <<= 1) sum += __shfl_xor(sum, d);
    __syncthreads();
    if (lane == 0) red[wv] = sum;
    __syncthreads();
    sum = red[0] + red[1] + red[2] + red[3];
    float w = e * (1.f / sum);
    wsm[tid] = w;
    if (chunk == 0) out[(size_t)NB * VIS_DIM + b * NR + tid] = w;
    __syncthreads();

    const float* vb = visual + ((size_t)b * NR + wv * 64) * VIS_DIM + chunk * 256 + lane * 4;
    f32x4 acc = {0.f, 0.f, 0.f, 0.f};
    #pragma unroll
    for (int r = 0; r < 64; r += 4) {
        f32x4 v0 = *(const f32x4*)(vb + (size_t)(r + 0) * VIS_DIM);
        f32x4 v1 = *(const f32x4*)(vb + (size_t)(r + 1) * VIS_DIM);
        f32x4 v2 = *(const f32x4*)(vb + (size_t)(r + 2) * VIS_DIM);
        f32x4 v3 = *(const f32x4*)(vb + (size_t)(r + 3) * VIS_DIM);
        acc += wsm[wv * 64 + r + 0] * v0;
        acc += wsm[wv * 64 + r + 1] * v1;
        acc += wsm[wv * 64 + r + 2] * v2;
        acc += wsm[wv * 64 + r + 3] * v3;
    }
    part[wv][lane] = acc;
    __syncthreads();
    if (wv == 0) {
        f32x4 a = part[0][lane] + part[1][lane] + part[2][lane] + part[3][lane];
        *(f32x4*)(out + (size_t)b * VIS_DIM + chunk * 256 + lane * 4) = a;
    }
}

// ---------------------------------------------------------------------------
extern "C" void kernel_launch(void* const* d_in, const int* in_sizes, int n_in,
                              void* d_out, int out_size, void* d_ws, size_t ws_size,
                              hipStream_t stream) {
    (void)in_sizes; (void)n_in; (void)out_size; (void)ws_size;
    const float* visual = (const float*)d_in[0];
    const float* text   = (const float*)d_in[1];
    const float* Wv     = (const float*)d_in[2];
    const float* bv     = (const float*)d_in[3];
    const float* Wt     = (const float*)d_in[4];
    const float* bt     = (const float*)d_in[5];
    const float* Wa     = (const float*)d_in[6];
    // d_in[7] = ba : softmax-shift-invariant, unused.

    float* out    = (float*)d_out;
    float* scores = (float*)d_ws;          // 32768 f32
    float* tbuf   = scores + M_TOT;        // 131072 f32  (total ws use: 640 KiB)

    init_ws  <<<512, 256, 0, stream>>>(scores, tbuf, bt);
    gemm_text<<<dim3(32, 4), 256, 0, stream>>>(text, Wt, tbuf);
    gemm_vis <<<2048, 256, 0, stream>>>(visual, Wv, bv, Wa, tbuf, scores);
    attend   <<<dim3(8, NB), 256, 0, stream>>>(visual, scores, out);
}